// Round 6
// baseline (250.324 us; speedup 1.0000x reference)
//
#include <hip/hip_runtime.h>

// GAT layer, CSR formulation. 5 dispatches:
//   K1  GEMM X@W.T -> H (+fused s_src/s_dst; zeroes count[] in preamble)
//   K2  packed[i]=dst<<16|src; count[dst]++   (edge-width detect inlined)
//   KS  single-block scan: rowstart = excl-scan(count)
//   KF  pos=atomicAdd(rowstart[dst]); csr16[pos]=src   (rowstart becomes row END)
//   KA  per-dst wave: coalesced edge preamble (w_l per lane) -> shfl-broadcast
//       H-gather loop; rs reconstructed as rowstart[dst]-deg. No max-shift
//       (softmax shift-invariant; e = s_src+s_dst is O(5), exp safe).

#define N_NODES 50000
#define N_EDGES 800000
#define IN_DIM  128
#define OUT_DIM 64
#define NEG_SLOPE 0.2f
#define NBLK_E    (N_EDGES / 256)           // 3125 exact

// workspace layout (4-byte element offsets)
#define WS_H      0                          // float N*64
#define WS_SSRC   (N_NODES * OUT_DIM)        // float N
#define WS_SDST   (WS_SSRC + N_NODES)        // float N
#define WS_PACK   (WS_SDST + N_NODES)        // uint E
#define WS_COUNT  (WS_PACK + N_EDGES)        // int N  (zeroed by gemm preamble)
#define WS_ROWST  (WS_COUNT + N_NODES)       // int N
#define WS_CSR16  (WS_ROWST + N_NODES)       // ushort E

// uniform-branch edge index fetch (int32 or int64 storage)
__device__ __forceinline__ int eidx(const void* ei, int use64, long long i) {
    return use64 ? (int)((const long long*)ei)[i] : ((const int*)ei)[i];
}

// K1: H = X @ W.T + per-node attention scalars; zeroes count[] first.
// 256 thr: cg = t&15 (4 cols), rg = t>>4 (4 rows) -> 4x4 micro-tile, 64-row tile.
__global__ __launch_bounds__(256) void gemm_kernel(
        const float* __restrict__ X, const float* __restrict__ W,
        const float* __restrict__ a_src, const float* __restrict__ a_dst,
        float* __restrict__ H, float* __restrict__ s_src, float* __restrict__ s_dst,
        int* __restrict__ count) {
    __shared__ float sWt[IN_DIM][OUT_DIM];   // 32 KB, k-major
    __shared__ float sX[64][76];             // 19 KB; pad 76 = 304B stride (16B-aligned)
    const int t = threadIdx.x;
    const int row0 = blockIdx.x * 64;
    const int cg = t & 15;
    const int rg = t >> 4;

    // zero the degree histogram (edge_pack runs after us in stream order)
    if (t < 64 && row0 + t < N_NODES) count[row0 + t] = 0;

    for (int i = t; i < 64 * 32; i += 256) {
        int col = i & 63, k4 = i >> 6;
        float4 w = reinterpret_cast<const float4*>(W)[col * 32 + k4];
        sWt[4 * k4 + 0][col] = w.x;
        sWt[4 * k4 + 1][col] = w.y;
        sWt[4 * k4 + 2][col] = w.z;
        sWt[4 * k4 + 3][col] = w.w;
    }

    float acc[4][4];
    #pragma unroll
    for (int i = 0; i < 4; ++i)
        #pragma unroll
        for (int j = 0; j < 4; ++j) acc[i][j] = 0.f;

    #pragma unroll
    for (int kk = 0; kk < 2; ++kk) {
        const int kb = kk * 64;
        __syncthreads();
        for (int i = t; i < 64 * 16; i += 256) {
            int k4 = i & 15, row = i >> 4;
            int grow = row0 + row;
            float4 x = make_float4(0.f, 0.f, 0.f, 0.f);
            if (grow < N_NODES)
                x = reinterpret_cast<const float4*>(X)[(size_t)grow * 32 + (kb >> 2) + k4];
            sX[4 * k4 + 0][row] = x.x;
            sX[4 * k4 + 1][row] = x.y;
            sX[4 * k4 + 2][row] = x.z;
            sX[4 * k4 + 3][row] = x.w;
        }
        __syncthreads();
        #pragma unroll 4
        for (int k = 0; k < 64; ++k) {
            float4 wv = *reinterpret_cast<const float4*>(&sWt[kb + k][cg * 4]);  // b128
            float4 xv = *reinterpret_cast<const float4*>(&sX[k][rg * 4]);        // b128
            acc[0][0] += xv.x * wv.x; acc[0][1] += xv.x * wv.y;
            acc[0][2] += xv.x * wv.z; acc[0][3] += xv.x * wv.w;
            acc[1][0] += xv.y * wv.x; acc[1][1] += xv.y * wv.y;
            acc[1][2] += xv.y * wv.z; acc[1][3] += xv.y * wv.w;
            acc[2][0] += xv.z * wv.x; acc[2][1] += xv.z * wv.y;
            acc[2][2] += xv.z * wv.z; acc[2][3] += xv.z * wv.w;
            acc[3][0] += xv.w * wv.x; acc[3][1] += xv.w * wv.y;
            acc[3][2] += xv.w * wv.z; acc[3][3] += xv.w * wv.w;
        }
    }

    float4 as = *reinterpret_cast<const float4*>(&a_src[cg * 4]);
    float4 ad = *reinterpret_cast<const float4*>(&a_dst[cg * 4]);
    #pragma unroll
    for (int i = 0; i < 4; ++i) {
        float ps = acc[i][0] * as.x + acc[i][1] * as.y + acc[i][2] * as.z + acc[i][3] * as.w;
        float pd = acc[i][0] * ad.x + acc[i][1] * ad.y + acc[i][2] * ad.z + acc[i][3] * ad.w;
        #pragma unroll
        for (int off = 1; off < 16; off <<= 1) {
            ps += __shfl_xor(ps, off);
            pd += __shfl_xor(pd, off);
        }
        int row = row0 + rg * 4 + i;
        if (row < N_NODES) {
            *reinterpret_cast<float4*>(&H[(size_t)row * OUT_DIM + cg * 4]) =
                make_float4(acc[i][0], acc[i][1], acc[i][2], acc[i][3]);
            if (cg == 0) { s_src[row] = ps; s_dst[row] = pd; }
        }
    }
}

// K2: packed = dst<<16|src; degree histogram. Edge-width detect inlined.
__global__ __launch_bounds__(256) void edge_pack_count_kernel(
        const void* __restrict__ ei, unsigned int* __restrict__ packed,
        int* __restrict__ count) {
    __shared__ int s_use64;
    if (threadIdx.x < 64) {
        unsigned int v = ((const unsigned int*)ei)[2 * threadIdx.x + 1];
        unsigned long long nz = __ballot(v != 0u);
        if (threadIdx.x == 0) s_use64 = (nz == 0ULL) ? 1 : 0;
    }
    __syncthreads();
    const int use64 = s_use64;
    const int i = blockIdx.x * 256 + threadIdx.x;      // grid exact
    int s = eidx(ei, use64, i);
    int d = eidx(ei, use64, (long long)N_EDGES + i);
    packed[i] = ((unsigned int)d << 16) | (unsigned int)s;
    atomicAdd(&count[d], 1);
}

// KS: single-block exclusive scan of count[N] -> rowstart.
// 1024 thr = 16 waves; 49 chunks with running carry.
__global__ __launch_bounds__(1024) void scan_kernel(
        const int* __restrict__ count, int* __restrict__ rowstart) {
    __shared__ int wsum[16];
    __shared__ int carry;
    const int t = threadIdx.x;
    const int lane = t & 63, wid = t >> 6;
    if (t == 0) carry = 0;
    __syncthreads();
    for (int base = 0; base < N_NODES; base += 1024) {
        int i = base + t;
        int v = (i < N_NODES) ? count[i] : 0;
        int incl = v;
        #pragma unroll
        for (int off = 1; off < 64; off <<= 1) {
            int n = __shfl_up(incl, off);
            if (lane >= off) incl += n;
        }
        if (lane == 63) wsum[wid] = incl;
        __syncthreads();
        if (t == 0) {
            int s = carry;
            #pragma unroll
            for (int w = 0; w < 16; ++w) { int tv = wsum[w]; wsum[w] = s; s += tv; }
            carry = s;
        }
        __syncthreads();
        int ex = wsum[wid] + incl - v;
        if (i < N_NODES) rowstart[i] = ex;
        __syncthreads();   // protect wsum from next chunk's writes
    }
}

// KF: bucket edges into CSR order (src only, 16-bit). Bumps rowstart in place;
// after this kernel rowstart[d] == segment END (= start + deg).
__global__ __launch_bounds__(256) void fill_kernel(
        const unsigned int* __restrict__ packed, int* __restrict__ rowstart,
        unsigned short* __restrict__ csr16) {
    const int i = blockIdx.x * 256 + threadIdx.x;      // grid exact
    unsigned int p = packed[i];
    int d = p >> 16;
    int pos = atomicAdd(&rowstart[d], 1);
    csr16[pos] = (unsigned short)(p & 0xFFFFu);
}

// KA: one wave per dst. Preamble: lane l owns edge rs+l -> coalesced csr16 load,
// one s_src gather, one exp; denom = wave reduce. Loop: shfl-broadcast (s,w),
// gather H row as 16 lanes x float4, 4 edges (eo) in flight.
__global__ __launch_bounds__(256) void aggregate_kernel(
        const float* __restrict__ H, const float* __restrict__ s_src,
        const float* __restrict__ s_dst, const int* __restrict__ count,
        const int* __restrict__ rowend, const unsigned short* __restrict__ csr16,
        float* __restrict__ out) {
    const int lane = threadIdx.x & 63;
    const int eo   = lane >> 4;
    const int cg   = lane & 15;
    const int dst  = blockIdx.x * 4 + (threadIdx.x >> 6);   // grid exact
    const int deg = count[dst];
    const int rs  = rowend[dst] - deg;        // fill bumped rowstart to end
    const float sd = s_dst[dst];

    int   sl = 0;
    float wl = 0.f;
    if (lane < deg) {
        sl = csr16[rs + lane];                // coalesced 128B wave load
        float tv = s_src[sl] + sd;
        tv = (tv >= 0.f) ? tv : NEG_SLOPE * tv;
        wl = expf(tv);
    }
    float denom = wl;
    #pragma unroll
    for (int off = 32; off; off >>= 1) denom += __shfl_xor(denom, off);

    float4 acc = make_float4(0.f, 0.f, 0.f, 0.f);
    const int n0 = (deg < 64) ? deg : 64;
    for (int j = 0; j < n0; j += 4) {
        int jj = j + eo;
        float w = __shfl(wl, jj);
        int   s = __shfl(sl, jj);
        if (jj >= n0) w = 0.f;               // s stays a valid node id
        float4 h = *reinterpret_cast<const float4*>(&H[(size_t)s * OUT_DIM + cg * 4]);
        acc.x += w * h.x; acc.y += w * h.y; acc.z += w * h.z; acc.w += w * h.w;
    }
    // tail for deg>64 (essentially cold for Poisson(16) degrees; kept for correctness)
    for (int jb = 64; jb < deg; jb += 64) {
        int jj = jb + lane;
        int s2 = 0; float w2 = 0.f;
        if (jj < deg) {
            s2 = csr16[rs + jj];
            float tv = s_src[s2] + sd;
            tv = (tv >= 0.f) ? tv : NEG_SLOPE * tv;
            w2 = expf(tv);
        }
        float d2 = w2;
        #pragma unroll
        for (int off = 32; off; off >>= 1) d2 += __shfl_xor(d2, off);
        denom += d2;
        const int n1 = (deg - jb < 64) ? (deg - jb) : 64;
        for (int j = 0; j < n1; j += 4) {
            int jj2 = j + eo;
            float w = __shfl(w2, jj2);
            int   s = __shfl(s2, jj2);
            if (jj2 >= n1) w = 0.f;
            float4 h = *reinterpret_cast<const float4*>(&H[(size_t)s * OUT_DIM + cg * 4]);
            acc.x += w * h.x; acc.y += w * h.y; acc.z += w * h.z; acc.w += w * h.w;
        }
    }

    acc.x += __shfl_xor(acc.x, 16); acc.y += __shfl_xor(acc.y, 16);
    acc.z += __shfl_xor(acc.z, 16); acc.w += __shfl_xor(acc.w, 16);
    acc.x += __shfl_xor(acc.x, 32); acc.y += __shfl_xor(acc.y, 32);
    acc.z += __shfl_xor(acc.z, 32); acc.w += __shfl_xor(acc.w, 32);
    if (eo == 0) {
        float inv = 1.f / (denom + 1e-12f);
        *reinterpret_cast<float4*>(&out[(size_t)dst * OUT_DIM + cg * 4]) =
            make_float4(acc.x * inv, acc.y * inv, acc.z * inv, acc.w * inv);
    }
}

extern "C" void kernel_launch(void* const* d_in, const int* in_sizes, int n_in,
                              void* d_out, int out_size, void* d_ws, size_t ws_size,
                              hipStream_t stream) {
    const float* X     = (const float*)d_in[0];
    const void*  ei    = d_in[1];                 // [2,E] int32 or int64 (detected)
    const float* W     = (const float*)d_in[3];
    const float* a_src = (const float*)d_in[4];
    const float* a_dst = (const float*)d_in[5];
    float* out = (float*)d_out;

    float* ws      = (float*)d_ws;
    float* H       = ws + WS_H;
    float* s_src   = ws + WS_SSRC;
    float* s_dst   = ws + WS_SDST;
    unsigned int* packed = (unsigned int*)(ws + WS_PACK);
    int*   count   = (int*)(ws + WS_COUNT);
    int*   rowst   = (int*)(ws + WS_ROWST);
    unsigned short* csr16 = (unsigned short*)(ws + WS_CSR16);

    gemm_kernel<<<(N_NODES + 63) / 64, 256, 0, stream>>>(X, W, a_src, a_dst, H, s_src, s_dst, count);
    edge_pack_count_kernel<<<NBLK_E, 256, 0, stream>>>(ei, packed, count);
    scan_kernel<<<1, 1024, 0, stream>>>(count, rowst);
    fill_kernel<<<NBLK_E, 256, 0, stream>>>(packed, rowst, csr16);
    aggregate_kernel<<<N_NODES / 4, 256, 0, stream>>>(H, s_src, s_dst, count, rowst, csr16, out);
}

// Round 8
// 211.689 us; speedup vs baseline: 1.1825x; 1.1825x over previous
//
#include <hip/hip_runtime.h>

// GAT layer, CSR formulation. 7 dispatches:
//   K1  GEMM X@W.T -> H (+fused s_src/s_dst; zeroes count[] in preamble)
//   K2  packed[i]=dst<<16|src; count[dst]++   (edge-width detect inlined)
//   S1-S3  3-kernel hierarchical scan: rowstart = excl-scan(count)
//   KF  XCD-sharded: shard=blockIdx&7 handles dst range [shard*6250,+6250);
//       pos=atomicAdd(rowstart[dst]); csr16[pos]=src  (writes L2-local per XCD)
//   KA  per-dst wave: coalesced edge preamble -> shfl-broadcast H-gather, 8 in flight.
// No max-shift (softmax shift-invariant; e = s_src+s_dst is O(5), exp safe).

#define N_NODES 50000
#define N_EDGES 800000
#define IN_DIM  128
#define OUT_DIM 64
#define NEG_SLOPE 0.2f
#define NBLK_E    (N_EDGES / 256)           // 3125 exact
#define NBLK_SCAN ((N_NODES + 255) / 256)   // 196
#define SHARD_W   6250                      // dst range per shard (50000/8)
#define FILL_BLKS 3200                      // 8 shards x 400 blocks
#define FILL_EPB  2048                      // edges scanned per block (400*2048 >= E)

// workspace layout (4-byte element offsets)
#define WS_H      0                          // float N*64
#define WS_SSRC   (N_NODES * OUT_DIM)        // float N
#define WS_SDST   (WS_SSRC + N_NODES)        // float N
#define WS_PACK   (WS_SDST + N_NODES)        // uint E
#define WS_COUNT  (WS_PACK + N_EDGES)        // int N  (zeroed by gemm preamble)
#define WS_ROWST  (WS_COUNT + N_NODES)       // int N
#define WS_BSUM   (WS_ROWST + N_NODES)       // int 256
#define WS_CSR16  (WS_BSUM + 256)            // ushort E

// uniform-branch edge index fetch (int32 or int64 storage)
__device__ __forceinline__ int eidx(const void* ei, int use64, long long i) {
    return use64 ? (int)((const long long*)ei)[i] : ((const int*)ei)[i];
}

// K1: H = X @ W.T + per-node attention scalars; zeroes count[] first.
// 256 thr: cg = t&15 (4 cols), rg = t>>4 (4 rows) -> 4x4 micro-tile, 64-row tile.
__global__ __launch_bounds__(256) void gemm_kernel(
        const float* __restrict__ X, const float* __restrict__ W,
        const float* __restrict__ a_src, const float* __restrict__ a_dst,
        float* __restrict__ H, float* __restrict__ s_src, float* __restrict__ s_dst,
        int* __restrict__ count) {
    __shared__ float sWt[IN_DIM][OUT_DIM];   // 32 KB, k-major
    __shared__ float sX[64][76];             // 19 KB; pad 76 = 304B stride (16B-aligned)
    const int t = threadIdx.x;
    const int row0 = blockIdx.x * 64;
    const int cg = t & 15;
    const int rg = t >> 4;

    if (t < 64 && row0 + t < N_NODES) count[row0 + t] = 0;

    for (int i = t; i < 64 * 32; i += 256) {
        int col = i & 63, k4 = i >> 6;
        float4 w = reinterpret_cast<const float4*>(W)[col * 32 + k4];
        sWt[4 * k4 + 0][col] = w.x;
        sWt[4 * k4 + 1][col] = w.y;
        sWt[4 * k4 + 2][col] = w.z;
        sWt[4 * k4 + 3][col] = w.w;
    }

    float acc[4][4];
    #pragma unroll
    for (int i = 0; i < 4; ++i)
        #pragma unroll
        for (int j = 0; j < 4; ++j) acc[i][j] = 0.f;

    #pragma unroll
    for (int kk = 0; kk < 2; ++kk) {
        const int kb = kk * 64;
        __syncthreads();
        for (int i = t; i < 64 * 16; i += 256) {
            int k4 = i & 15, row = i >> 4;
            int grow = row0 + row;
            float4 x = make_float4(0.f, 0.f, 0.f, 0.f);
            if (grow < N_NODES)
                x = reinterpret_cast<const float4*>(X)[(size_t)grow * 32 + (kb >> 2) + k4];
            sX[4 * k4 + 0][row] = x.x;
            sX[4 * k4 + 1][row] = x.y;
            sX[4 * k4 + 2][row] = x.z;
            sX[4 * k4 + 3][row] = x.w;
        }
        __syncthreads();
        #pragma unroll 4
        for (int k = 0; k < 64; ++k) {
            float4 wv = *reinterpret_cast<const float4*>(&sWt[kb + k][cg * 4]);  // b128
            float4 xv = *reinterpret_cast<const float4*>(&sX[k][rg * 4]);        // b128
            acc[0][0] += xv.x * wv.x; acc[0][1] += xv.x * wv.y;
            acc[0][2] += xv.x * wv.z; acc[0][3] += xv.x * wv.w;
            acc[1][0] += xv.y * wv.x; acc[1][1] += xv.y * wv.y;
            acc[1][2] += xv.y * wv.z; acc[1][3] += xv.y * wv.w;
            acc[2][0] += xv.z * wv.x; acc[2][1] += xv.z * wv.y;
            acc[2][2] += xv.z * wv.z; acc[2][3] += xv.z * wv.w;
            acc[3][0] += xv.w * wv.x; acc[3][1] += xv.w * wv.y;
            acc[3][2] += xv.w * wv.z; acc[3][3] += xv.w * wv.w;
        }
    }

    float4 as = *reinterpret_cast<const float4*>(&a_src[cg * 4]);
    float4 ad = *reinterpret_cast<const float4*>(&a_dst[cg * 4]);
    #pragma unroll
    for (int i = 0; i < 4; ++i) {
        float ps = acc[i][0] * as.x + acc[i][1] * as.y + acc[i][2] * as.z + acc[i][3] * as.w;
        float pd = acc[i][0] * ad.x + acc[i][1] * ad.y + acc[i][2] * ad.z + acc[i][3] * ad.w;
        #pragma unroll
        for (int off = 1; off < 16; off <<= 1) {
            ps += __shfl_xor(ps, off);
            pd += __shfl_xor(pd, off);
        }
        int row = row0 + rg * 4 + i;
        if (row < N_NODES) {
            *reinterpret_cast<float4*>(&H[(size_t)row * OUT_DIM + cg * 4]) =
                make_float4(acc[i][0], acc[i][1], acc[i][2], acc[i][3]);
            if (cg == 0) { s_src[row] = ps; s_dst[row] = pd; }
        }
    }
}

// K2: packed = dst<<16|src; degree histogram. Edge-width detect inlined.
__global__ __launch_bounds__(256) void edge_pack_count_kernel(
        const void* __restrict__ ei, unsigned int* __restrict__ packed,
        int* __restrict__ count) {
    __shared__ int s_use64;
    if (threadIdx.x < 64) {
        unsigned int v = ((const unsigned int*)ei)[2 * threadIdx.x + 1];
        unsigned long long nz = __ballot(v != 0u);
        if (threadIdx.x == 0) s_use64 = (nz == 0ULL) ? 1 : 0;
    }
    __syncthreads();
    const int use64 = s_use64;
    const int i = blockIdx.x * 256 + threadIdx.x;      // grid exact
    int s = eidx(ei, use64, i);
    int d = eidx(ei, use64, (long long)N_EDGES + i);
    packed[i] = ((unsigned int)d << 16) | (unsigned int)s;
    atomicAdd(&count[d], 1);
}

// ---- 3-kernel hierarchical exclusive scan of count[N] -> rowstart ----
__device__ __forceinline__ int block_excl_scan_256(int x, int* lds4) {
    const int lane = threadIdx.x & 63;
    const int wid  = threadIdx.x >> 6;
    int incl = x;
    #pragma unroll
    for (int off = 1; off < 64; off <<= 1) {
        int n = __shfl_up(incl, off);
        if (lane >= off) incl += n;
    }
    if (lane == 63) lds4[wid] = incl;
    __syncthreads();
    if (threadIdx.x == 0) {
        int s = 0;
        #pragma unroll
        for (int w = 0; w < 4; ++w) { int tv = lds4[w]; lds4[w] = s; s += tv; }
    }
    __syncthreads();
    return lds4[wid] + incl - x;
}

__global__ __launch_bounds__(256) void scan1_kernel(const int* __restrict__ count,
                                                    int* __restrict__ blockSum) {
    int i = blockIdx.x * 256 + threadIdx.x;
    int v = (i < N_NODES) ? count[i] : 0;
    #pragma unroll
    for (int off = 32; off; off >>= 1) v += __shfl_xor(v, off);
    __shared__ int lds4[4];
    if ((threadIdx.x & 63) == 0) lds4[threadIdx.x >> 6] = v;
    __syncthreads();
    if (threadIdx.x == 0) blockSum[blockIdx.x] = lds4[0] + lds4[1] + lds4[2] + lds4[3];
}

__global__ __launch_bounds__(256) void scan2_kernel(int* __restrict__ blockSum) {
    __shared__ int lds4[4];
    int v = (threadIdx.x < NBLK_SCAN) ? blockSum[threadIdx.x] : 0;
    int ex = block_excl_scan_256(v, lds4);
    if (threadIdx.x < NBLK_SCAN) blockSum[threadIdx.x] = ex;
}

__global__ __launch_bounds__(256) void scan3_kernel(const int* __restrict__ count,
                                                    const int* __restrict__ blockOfs,
                                                    int* __restrict__ rowstart) {
    __shared__ int lds4[4];
    int i = blockIdx.x * 256 + threadIdx.x;
    int v = (i < N_NODES) ? count[i] : 0;
    int ex = block_excl_scan_256(v, lds4) + blockOfs[blockIdx.x];
    if (i < N_NODES) rowstart[i] = ex;
}

// KF: XCD-sharded CSR fill. shard = blockIdx&7 handles dst in [shard*6250,+6250).
// Under blockIdx%8 -> XCD round-robin, all writes to a dst range stay in ONE
// XCD's L2 -> lines merge, writebacks collapse (was 40.7MB for 1.6MB payload).
// Costs 8x re-read of packed (L3-served). Correct under any block->XCD mapping.
// After this kernel rowstart[d] == segment END (= start + deg).
__global__ __launch_bounds__(256) void fill_kernel(
        const unsigned int* __restrict__ packed, int* __restrict__ rowstart,
        unsigned short* __restrict__ csr16) {
    const int shard = blockIdx.x & 7;
    const int bslot = blockIdx.x >> 3;
    const unsigned int dlo = shard * SHARD_W;
    const int base = bslot * FILL_EPB;
    for (int j = 0; j < FILL_EPB / 256; ++j) {
        int i = base + j * 256 + threadIdx.x;
        if (i < N_EDGES) {
            unsigned int p = packed[i];
            unsigned int d = p >> 16;
            if (d - dlo < SHARD_W) {
                int pos = atomicAdd(&rowstart[d], 1);
                csr16[pos] = (unsigned short)(p & 0xFFFFu);
            }
        }
    }
}

// KA: one wave per dst. Preamble: lane l owns edge rs+l (coalesced csr16 load,
// one s_src gather, one exp); denom = wave reduce. Loop: shfl-broadcast (s,w),
// 8 H-row gathers in flight (two 4-edge groups), 16 lanes x float4 per row.
__global__ __launch_bounds__(256) void aggregate_kernel(
        const float* __restrict__ H, const float* __restrict__ s_src,
        const float* __restrict__ s_dst, const int* __restrict__ count,
        const int* __restrict__ rowend, const unsigned short* __restrict__ csr16,
        float* __restrict__ out) {
    const int lane = threadIdx.x & 63;
    const int eo   = lane >> 4;
    const int cg   = lane & 15;
    const int dst  = blockIdx.x * 4 + (threadIdx.x >> 6);   // grid exact
    const int deg = count[dst];
    const int rs  = rowend[dst] - deg;        // fill bumped rowstart to end
    const float sd = s_dst[dst];

    int   sl = 0;
    float wl = 0.f;
    if (lane < deg) {
        sl = csr16[rs + lane];                // coalesced 128B wave load
        float tv = s_src[sl] + sd;
        tv = (tv >= 0.f) ? tv : NEG_SLOPE * tv;
        wl = expf(tv);
    }
    float denom = wl;
    #pragma unroll
    for (int off = 32; off; off >>= 1) denom += __shfl_xor(denom, off);

    float4 acc = make_float4(0.f, 0.f, 0.f, 0.f);
    const int n0 = (deg < 64) ? deg : 64;
    for (int j = 0; j < n0; j += 8) {
        int ja = j + eo, jb = j + 4 + eo;
        float wa = __shfl(wl, ja);
        int   sa = __shfl(sl, ja);
        float wb = __shfl(wl, jb);
        int   sb = __shfl(sl, jb);
        if (ja >= n0) wa = 0.f;
        if (jb >= n0) wb = 0.f;
        float4 ha = *reinterpret_cast<const float4*>(&H[(size_t)sa * OUT_DIM + cg * 4]);
        float4 hb = *reinterpret_cast<const float4*>(&H[(size_t)sb * OUT_DIM + cg * 4]);
        acc.x += wa * ha.x + wb * hb.x;
        acc.y += wa * ha.y + wb * hb.y;
        acc.z += wa * ha.z + wb * hb.z;
        acc.w += wa * ha.w + wb * hb.w;
    }
    // tail for deg>64 (cold for Poisson(16) degrees; kept for correctness)
    for (int jb0 = 64; jb0 < deg; jb0 += 64) {
        int jj = jb0 + lane;
        int s2 = 0; float w2 = 0.f;
        if (jj < deg) {
            s2 = csr16[rs + jj];
            float tv = s_src[s2] + sd;
            tv = (tv >= 0.f) ? tv : NEG_SLOPE * tv;
            w2 = expf(tv);
        }
        float d2 = w2;
        #pragma unroll
        for (int off = 32; off; off >>= 1) d2 += __shfl_xor(d2, off);
        denom += d2;
        const int n1 = (deg - jb0 < 64) ? (deg - jb0) : 64;
        for (int j = 0; j < n1; j += 4) {
            int jj2 = j + eo;
            float w = __shfl(w2, jj2);
            int   s = __shfl(s2, jj2);
            if (jj2 >= n1) w = 0.f;
            float4 h = *reinterpret_cast<const float4*>(&H[(size_t)s * OUT_DIM + cg * 4]);
            acc.x += w * h.x; acc.y += w * h.y; acc.z += w * h.z; acc.w += w * h.w;
        }
    }

    acc.x += __shfl_xor(acc.x, 16); acc.y += __shfl_xor(acc.y, 16);
    acc.z += __shfl_xor(acc.z, 16); acc.w += __shfl_xor(acc.w, 16);
    acc.x += __shfl_xor(acc.x, 32); acc.y += __shfl_xor(acc.y, 32);
    acc.z += __shfl_xor(acc.z, 32); acc.w += __shfl_xor(acc.w, 32);
    if (eo == 0) {
        float inv = 1.f / (denom + 1e-12f);
        *reinterpret_cast<float4*>(&out[(size_t)dst * OUT_DIM + cg * 4]) =
            make_float4(acc.x * inv, acc.y * inv, acc.z * inv, acc.w * inv);
    }
}

extern "C" void kernel_launch(void* const* d_in, const int* in_sizes, int n_in,
                              void* d_out, int out_size, void* d_ws, size_t ws_size,
                              hipStream_t stream) {
    const float* X     = (const float*)d_in[0];
    const void*  ei    = d_in[1];                 // [2,E] int32 or int64 (detected)
    const float* W     = (const float*)d_in[3];
    const float* a_src = (const float*)d_in[4];
    const float* a_dst = (const float*)d_in[5];
    float* out = (float*)d_out;

    float* ws      = (float*)d_ws;
    float* H       = ws + WS_H;
    float* s_src   = ws + WS_SSRC;
    float* s_dst   = ws + WS_SDST;
    unsigned int* packed = (unsigned int*)(ws + WS_PACK);
    int*   count   = (int*)(ws + WS_COUNT);
    int*   rowst   = (int*)(ws + WS_ROWST);
    int*   bsum    = (int*)(ws + WS_BSUM);
    unsigned short* csr16 = (unsigned short*)(ws + WS_CSR16);

    gemm_kernel<<<(N_NODES + 63) / 64, 256, 0, stream>>>(X, W, a_src, a_dst, H, s_src, s_dst, count);
    edge_pack_count_kernel<<<NBLK_E, 256, 0, stream>>>(ei, packed, count);
    scan1_kernel<<<NBLK_SCAN, 256, 0, stream>>>(count, bsum);
    scan2_kernel<<<1, 256, 0, stream>>>(bsum);
    scan3_kernel<<<NBLK_SCAN, 256, 0, stream>>>(count, bsum, rowst);
    fill_kernel<<<FILL_BLKS, 256, 0, stream>>>(packed, rowst, csr16);
    aggregate_kernel<<<N_NODES / 4, 256, 0, stream>>>(H, s_src, s_dst, count, rowst, csr16, out);
}